// Round 1
// baseline (82.723 us; speedup 1.0000x reference)
//
#include <hip/hip_runtime.h>
#include <math.h>

#define DEV __device__ __forceinline__

DEV float gelu_exact(float x) {
    return 0.5f * x * (1.0f + erff(x * 0.70710678118654752f));
}

// ---------------- K1: adjacency bitmask ----------------
// grid = 500 blocks (one per row i), block = 512 threads (8 waves), lane j.
// mask[i][j] = (cos_sim(emb[i], emb[j]) > 0.5), stored as 8 u64 words per row.
__global__ __launch_bounds__(512)
void mask_kernel(const float* __restrict__ emb,
                 unsigned long long* __restrict__ maskw) {
    const int i = blockIdx.x;
    const int j = threadIdx.x;
    float ei[8], ej[8];
    float si = 0.f, sj = 0.f;
#pragma unroll
    for (int e = 0; e < 8; ++e) { ei[e] = emb[i * 8 + e]; si += ei[e] * ei[e]; }
    const int jj = (j < 500) ? j : 0;
#pragma unroll
    for (int e = 0; e < 8; ++e) { ej[e] = emb[jj * 8 + e]; sj += ej[e] * ej[e]; }
    const float ri = 1.0f / sqrtf(si);
    const float rj = 1.0f / sqrtf(sj);
    float dot = 0.f;
#pragma unroll
    for (int e = 0; e < 8; ++e) dot += (ei[e] * ri) * (ej[e] * rj);
    const bool pred = (j < 500) && (dot > 0.5f);
    unsigned long long m = __ballot(pred);
    if ((threadIdx.x & 63) == 0) maskw[i * 8 + (threadIdx.x >> 6)] = m;
}

// ---------------- K2/K3: fused GAT layer ----------------
// grid = 96 graphs * 4 heads = 384 blocks, block = 256 threads.
// Per block: stage features, compute per-head projection h1 + attention
// logits s_src/s_dst in LDS, then sparse-softmax aggregate via bitmask.
template <int INF, int C, bool PROJ, bool GELU_OUT>
__global__ __launch_bounds__(256)
void gat_kernel(const float* __restrict__ in,   // PROJ ? [96,500,3] : [96,500,INF]
                const float* __restrict__ pw,   // [3,INF] (PROJ only)
                const float* __restrict__ pb,   // [INF]
                const float* __restrict__ W,    // [INF,4,C]
                const float* __restrict__ asrc, // [4,C]
                const float* __restrict__ adst, // [4,C]
                const float* __restrict__ bias, // [4*C]
                const unsigned long long* __restrict__ maskw, // [500][8]
                float* __restrict__ out) {      // [96,500,4*C]
    const int b = blockIdx.x >> 2;
    const int head = blockIdx.x & 3;
    const int tid = threadIdx.x;
    __shared__ float xh[500][INF + 1];
    __shared__ float h1[500][C + 1];
    __shared__ float ssrc[500];
    __shared__ float sdst[500];

    // step 1: stage input features (optionally fused dense proj)
    for (int n = tid; n < 500; n += 256) {
        if constexpr (PROJ) {
            const float* xr = in + ((size_t)b * 500 + n) * 3;
            const float x0 = xr[0], x1 = xr[1], x2 = xr[2];
#pragma unroll
            for (int e = 0; e < INF; ++e)
                xh[n][e] = x0 * pw[0 * INF + e] + x1 * pw[1 * INF + e] +
                           x2 * pw[2 * INF + e] + pb[e];
        } else {
            const float* xr = in + ((size_t)b * 500 + n) * INF;
#pragma unroll
            for (int e = 0; e < INF; ++e) xh[n][e] = xr[e];
        }
    }
    __syncthreads();

    // step 2: h1 = xh @ W[:,head,:]; s_src/s_dst
    for (int n = tid; n < 500; n += 256) {
        float acc[C];
#pragma unroll
        for (int c = 0; c < C; ++c) acc[c] = 0.f;
#pragma unroll
        for (int e = 0; e < INF; ++e) {
            const float xv = xh[n][e];
#pragma unroll
            for (int c = 0; c < C; ++c) acc[c] += xv * W[(e * 4 + head) * C + c];
        }
        float ss = 0.f, sd = 0.f;
#pragma unroll
        for (int c = 0; c < C; ++c) {
            h1[n][c] = acc[c];
            ss += acc[c] * asrc[head * C + c];
            sd += acc[c] * adst[head * C + c];
        }
        ssrc[n] = ss;
        sdst[n] = sd;
    }
    __syncthreads();

    // step 3: masked rank-1 softmax aggregation (bit-scan over neighbors)
    for (int i = tid; i < 500; i += 256) {
        const float d = sdst[i];
        float num[C];
#pragma unroll
        for (int c = 0; c < C; ++c) num[c] = 0.f;
        float den = 0.f;
#pragma unroll 1
        for (int wi = 0; wi < 8; ++wi) {
            unsigned long long m = maskw[i * 8 + wi];
            while (m) {
                const int bit = __ffsll(m) - 1;
                m &= (m - 1);
                const int j = wi * 64 + bit;
                float e = d + ssrc[j];
                e = (e > 0.f) ? e : 0.2f * e;
                const float w_ = __expf(e);
                den += w_;
#pragma unroll
                for (int c = 0; c < C; ++c) num[c] += w_ * h1[j][c];
            }
        }
        const float inv = 1.0f / den;  // diag self-loop guarantees den > 0
        float* orow = out + ((size_t)b * 500 + i) * (4 * C) + head * C;
#pragma unroll
        for (int c = 0; c < C; ++c) {
            float v = num[c] * inv + bias[head * C + c];
            if constexpr (GELU_OUT) v = gelu_exact(v);
            orow[c] = v;
        }
    }
}

// ---------------- K4: transformer + pool + regressor ----------------
// grid = 2000 sequences, block = 64 threads (1 wave).
__global__ __launch_bounds__(64)
void transformer_kernel(const float* __restrict__ tin,  // [2000,24,16] raw reshape
                        const float* __restrict__ wq, const float* __restrict__ bq,
                        const float* __restrict__ wk, const float* __restrict__ bk,
                        const float* __restrict__ wv, const float* __restrict__ bv,
                        const float* __restrict__ wo, const float* __restrict__ bo,
                        const float* __restrict__ ln1g, const float* __restrict__ ln1b,
                        const float* __restrict__ ln2g, const float* __restrict__ ln2b,
                        const float* __restrict__ fw1, const float* __restrict__ fb1,
                        const float* __restrict__ fw2, const float* __restrict__ fb2,
                        const float* __restrict__ rw1, const float* __restrict__ rb1,
                        const float* __restrict__ rw2, const float* __restrict__ rb2,
                        float* __restrict__ outp) {
    const int r = blockIdx.x;
    const int lane = threadIdx.x;
    __shared__ float t0[24][16], qs[24][16], ks[24][16], vs[24][16];
    __shared__ float os[24][16], t1[24][16], hid[24][32], pooled[16];

    const float* row = tin + (size_t)r * 384;
    for (int idx = lane; idx < 384; idx += 64) t0[idx >> 4][idx & 15] = row[idx];
    __syncthreads();

    // QKV: q[s,h,d] = sum_e t0[s,e] * wq[e,h,d] + bq[h,d]  (f = h*8+d in 0..15)
    for (int idx = lane; idx < 384; idx += 64) {
        const int s = idx >> 4, f = idx & 15;
        float aq = bq[f], ak = bk[f], av = bv[f];
#pragma unroll
        for (int e = 0; e < 16; ++e) {
            const float tv = t0[s][e];
            aq += tv * wq[e * 16 + f];
            ak += tv * wk[e * 16 + f];
            av += tv * wv[e * 16 + f];
        }
        qs[s][f] = aq; ks[s][f] = ak; vs[s][f] = av;
    }
    __syncthreads();

    // attention: lane = h*24 + s for lane < 48
    if (lane < 48) {
        const int h = lane / 24, s = lane % 24;
        float sc[24];
        float mx = -1e30f;
#pragma unroll
        for (int t = 0; t < 24; ++t) {
            float a = 0.f;
#pragma unroll
            for (int d2 = 0; d2 < 8; ++d2) a += qs[s][h * 8 + d2] * ks[t][h * 8 + d2];
            a *= 0.35355339059327373f;  // 1/sqrt(8)
            sc[t] = a;
            mx = fmaxf(mx, a);
        }
        float sum = 0.f;
#pragma unroll
        for (int t = 0; t < 24; ++t) { sc[t] = __expf(sc[t] - mx); sum += sc[t]; }
        const float inv = 1.0f / sum;
#pragma unroll
        for (int d2 = 0; d2 < 8; ++d2) {
            float acc = 0.f;
#pragma unroll
            for (int t = 0; t < 24; ++t) acc += sc[t] * vs[t][h * 8 + d2];
            os[s][h * 8 + d2] = acc * inv;
        }
    }
    __syncthreads();

    // out-proj + residual + LN1 (one lane per row s)
    if (lane < 24) {
        const int s = lane;
        float x[16];
#pragma unroll
        for (int d = 0; d < 16; ++d) {
            float a = bo[d];
#pragma unroll
            for (int hd = 0; hd < 16; ++hd) a += os[s][hd] * wo[hd * 16 + d];
            x[d] = t0[s][d] + a;
        }
        float mean = 0.f;
#pragma unroll
        for (int d = 0; d < 16; ++d) mean += x[d];
        mean *= (1.0f / 16.0f);
        float var = 0.f;
#pragma unroll
        for (int d = 0; d < 16; ++d) { const float t = x[d] - mean; var += t * t; }
        var *= (1.0f / 16.0f);
        const float rs = 1.0f / sqrtf(var + 1e-3f);
#pragma unroll
        for (int d = 0; d < 16; ++d) t1[s][d] = (x[d] - mean) * rs * ln1g[d] + ln1b[d];
    }
    __syncthreads();

    // FFN hidden: [24,32]
    for (int idx = lane; idx < 768; idx += 64) {
        const int s = idx >> 5, f = idx & 31;
        float a = fb1[f];
#pragma unroll
        for (int e = 0; e < 16; ++e) a += t1[s][e] * fw1[e * 32 + f];
        hid[s][f] = gelu_exact(a);
    }
    __syncthreads();

    // FFN out + residual + LN2 (each lane owns row s; overwrites t1[s])
    if (lane < 24) {
        const int s = lane;
        float x[16];
#pragma unroll
        for (int d = 0; d < 16; ++d) {
            float a = fb2[d];
#pragma unroll
            for (int f = 0; f < 32; ++f) a += hid[s][f] * fw2[f * 16 + d];
            x[d] = t1[s][d] + a;
        }
        float mean = 0.f;
#pragma unroll
        for (int d = 0; d < 16; ++d) mean += x[d];
        mean *= (1.0f / 16.0f);
        float var = 0.f;
#pragma unroll
        for (int d = 0; d < 16; ++d) { const float t = x[d] - mean; var += t * t; }
        var *= (1.0f / 16.0f);
        const float rs = 1.0f / sqrtf(var + 1e-3f);
#pragma unroll
        for (int d = 0; d < 16; ++d) t1[s][d] = (x[d] - mean) * rs * ln2g[d] + ln2b[d];
    }
    __syncthreads();

    // mean-pool over T
    if (lane < 16) {
        float a = 0.f;
#pragma unroll
        for (int s = 0; s < 24; ++s) a += t1[s][lane];
        pooled[lane] = a * (1.0f / 24.0f);
    }
    __syncthreads();

    // regressor: gelu(pooled @ rw1 + rb1) @ rw2 + rb2
    float partial = 0.f;
    if (lane < 16) {
        float a = rb1[lane];
#pragma unroll
        for (int e = 0; e < 16; ++e) a += pooled[e] * rw1[e * 16 + lane];
        partial = gelu_exact(a) * rw2[lane];
    }
    partial += __shfl_xor(partial, 8);
    partial += __shfl_xor(partial, 4);
    partial += __shfl_xor(partial, 2);
    partial += __shfl_xor(partial, 1);
    if (lane == 0) outp[r] = partial + rb2[0];
}

extern "C" void kernel_launch(void* const* d_in, const int* in_sizes, int n_in,
                              void* d_out, int out_size, void* d_ws, size_t ws_size,
                              hipStream_t stream) {
    const float* x      = (const float*)d_in[0];
    const float* emb    = (const float*)d_in[1];
    const float* proj_w = (const float*)d_in[2];
    const float* proj_b = (const float*)d_in[3];
    const float* g1_w   = (const float*)d_in[4];
    const float* g1_as  = (const float*)d_in[5];
    const float* g1_ad  = (const float*)d_in[6];
    const float* g1_b   = (const float*)d_in[7];
    const float* g2_w   = (const float*)d_in[8];
    const float* g2_as  = (const float*)d_in[9];
    const float* g2_ad  = (const float*)d_in[10];
    const float* g2_b   = (const float*)d_in[11];
    const float* wq = (const float*)d_in[12];
    const float* bq = (const float*)d_in[13];
    const float* wk = (const float*)d_in[14];
    const float* bk = (const float*)d_in[15];
    const float* wv = (const float*)d_in[16];
    const float* bv = (const float*)d_in[17];
    const float* wo = (const float*)d_in[18];
    const float* bo = (const float*)d_in[19];
    const float* ln1g = (const float*)d_in[20];
    const float* ln1b = (const float*)d_in[21];
    const float* ln2g = (const float*)d_in[22];
    const float* ln2b = (const float*)d_in[23];
    const float* fw1 = (const float*)d_in[24];
    const float* fb1 = (const float*)d_in[25];
    const float* fw2 = (const float*)d_in[26];
    const float* fb2 = (const float*)d_in[27];
    const float* rw1 = (const float*)d_in[28];
    const float* rb1 = (const float*)d_in[29];
    const float* rw2 = (const float*)d_in[30];
    const float* rb2 = (const float*)d_in[31];

    // workspace layout
    unsigned long long* maskw = (unsigned long long*)d_ws;          // 32000 B (pad 32768)
    float* h_g1  = (float*)((char*)d_ws + 32768);                   // 96*500*8*4  = 1,536,000 B
    float* t_buf = (float*)((char*)d_ws + 32768 + 1536000);         // 96*500*16*4 = 3,072,000 B

    mask_kernel<<<500, 512, 0, stream>>>(emb, maskw);
    gat_kernel<8, 2, true, true><<<384, 256, 0, stream>>>(
        x, proj_w, proj_b, g1_w, g1_as, g1_ad, g1_b, maskw, h_g1);
    gat_kernel<8, 4, false, false><<<384, 256, 0, stream>>>(
        h_g1, nullptr, nullptr, g2_w, g2_as, g2_ad, g2_b, maskw, t_buf);
    transformer_kernel<<<2000, 64, 0, stream>>>(
        t_buf, wq, bq, wk, bk, wv, bv, wo, bo, ln1g, ln1b, ln2g, ln2b,
        fw1, fb1, fw2, fb2, rw1, rb1, rw2, rb2, (float*)d_out);
}